// Round 1
// 582.558 us; speedup vs baseline: 1.0253x; 1.0253x over previous
//
#include <hip/hip_runtime.h>
#include <hip/hip_bf16.h>

typedef unsigned short u16;
typedef unsigned int   u32;

typedef __bf16 bf16x8 __attribute__((ext_vector_type(8)));
typedef float  f32x4  __attribute__((ext_vector_type(4)));

// ---------- helpers ----------
__device__ __forceinline__ u16 f2bf(float f) {  // RNE
  u32 u = __float_as_uint(f);
  u += 0x7fffu + ((u >> 16) & 1u);
  return (u16)(u >> 16);
}
__device__ __forceinline__ u32 pack2(float a, float b) {
  return (u32)f2bf(a) | ((u32)f2bf(b) << 16);
}
__device__ __forceinline__ void gld16(const void* g, void* l) {
  __builtin_amdgcn_global_load_lds(
      (const __attribute__((address_space(1))) unsigned int*)g,
      (__attribute__((address_space(3))) unsigned int*)l, 16, 0, 0);
}

// Problem constants
#define TOK_M   78848   // B*N = 8*9856
#define DIM     256
#define NWIN    1024    // 8 * 8 * 16
#define WINL    77      // 7*11

// ---------- weight f32 -> bf16 conversion (all 4 matrices, one launch) ----------
__global__ __launch_bounds__(256)
void cvt_w(const float* __restrict__ w0, const float* __restrict__ w1,
           const float* __restrict__ w2, const float* __restrict__ w3,
           u16* __restrict__ out)
{
  const int i = (blockIdx.x * 256 + threadIdx.x) * 4;  // [0, 524288)
  const float* src; int off;
  if      (i < 196608) { src = w0; off = i; }
  else if (i < 262144) { src = w1; off = i - 196608; }
  else if (i < 393216) { src = w2; off = i - 262144; }
  else                 { src = w3; off = i - 393216; }
  float4 v = *(const float4*)(src + off);
  uint2 o; o.x = pack2(v.x, v.y); o.y = pack2(v.z, v.w);
  *(uint2*)(out + i) = o;
}

// ---------- LayerNorm (+ optional window-partition permutation), fp32 in, bf16 out ----------
template<bool PERM>
__global__ __launch_bounds__(256)
void ln_k(const float* __restrict__ X, const float* __restrict__ g,
          const float* __restrict__ bta, u16* __restrict__ Y)
{
  const int tid  = threadIdx.x;
  const int tok  = blockIdx.x * 4 + (tid >> 6);
  const int lane = tid & 63;
  float4 v = *(const float4*)(X + (size_t)tok * DIM + lane * 4);
  float s = v.x + v.y + v.z + v.w;
#pragma unroll
  for (int off = 32; off; off >>= 1) s += __shfl_xor(s, off);
  const float mu = s * (1.f / 256.f);
  const float dx = v.x - mu, dy = v.y - mu, dz = v.z - mu, dw = v.w - mu;
  float q = dx * dx + dy * dy + dz * dz + dw * dw;
#pragma unroll
  for (int off = 32; off; off >>= 1) q += __shfl_xor(q, off);
  const float rstd = rsqrtf(q * (1.f / 256.f) + 1e-5f);
  float4 gg = *(const float4*)(g + lane * 4);
  float4 bb = *(const float4*)(bta + lane * 4);
  const float y0 = dx * rstd * gg.x + bb.x;
  const float y1 = dy * rstd * gg.y + bb.y;
  const float y2 = dz * rstd * gg.z + bb.z;
  const float y3 = dw * rstd * gg.w + bb.w;
  size_t dest = (size_t)tok;
  if (PERM) {
    const int b  = tok / 9856, n = tok - b * 9856;
    const int y  = n / 176,  xc = n - y * 176;
    const int ih = y / 7,    rr = y - ih * 7;
    const int iw = xc / 11,  cc = xc - iw * 11;
    dest = (size_t)(((b * 8 + ih) * 16 + iw)) * 77 + rr * 11 + cc;
  }
  uint2 o;
  o.x = pack2(y0, y1);
  o.y = pack2(y2, y3);
  *(uint2*)(Y + dest * DIM + lane * 4) = o;
}

// ---------- MFMA GEMM: C[M,N] = A(bf16)[M,K] @ W(bf16)[N,K]^T + bias (+epi) ----------
// 2-phase double-buffered K-loop: stage tile t+1 while computing tile t.
// Grid: blockIdx.x = column(N)-block (fast, shares A panel in L2),
//       blockIdx.y = row(M)-block.
template<int EPI, int OBF>
__global__ __launch_bounds__(256, 3)
void gemm_mfma(const u16* __restrict__ A, const u16* __restrict__ W,
               const float* __restrict__ bias, const float* res,
               void* Cout, int N, int K)
{
  __shared__ u16 As[2][4096];  // per buf: 128 rows x 32 elems (4x 16B blocks/row, swizzled)
  __shared__ u16 Bs[2][4096];

  const int tid  = threadIdx.x;
  const int wave = tid >> 6, lane = tid & 63;
  const int wy = wave >> 1, wx = wave & 1;
  const int quad = lane >> 4, l16 = lane & 15;
  const int m0 = blockIdx.y * 128;
  const int n0 = blockIdx.x * 128;

  const int s0 = tid, s1 = tid + 256;
  const int r0 = s0 >> 2, r1 = s1 >> 2;
  const int kb0 = (s0 & 3) ^ (r0 & 3);
  const int kb1 = (s1 & 3) ^ (r1 & 3);
  const u16* Ag0 = A + (size_t)(m0 + r0) * K + kb0 * 8;
  const u16* Ag1 = A + (size_t)(m0 + r1) * K + kb1 * 8;
  const u16* Bg0 = W + (size_t)(n0 + r0) * K + kb0 * 8;
  const u16* Bg1 = W + (size_t)(n0 + r1) * K + kb1 * 8;

  const int kbs = quad ^ (l16 & 3);
  const int aoff = (wy * 64 + l16) * 32 + kbs * 8;
  const int boff = (wx * 64 + l16) * 32 + kbs * 8;

  f32x4 acc[4][4];
#pragma unroll
  for (int i = 0; i < 4; ++i)
#pragma unroll
    for (int j = 0; j < 4; ++j) {
      f32x4 z = {0.f, 0.f, 0.f, 0.f};
      acc[i][j] = z;
    }

  // prologue: stage tile 0 into buffer 0
  gld16(Ag0, &As[0][s0 * 8]);
  gld16(Ag1, &As[0][s1 * 8]);
  gld16(Bg0, &Bs[0][s0 * 8]);
  gld16(Bg1, &Bs[0][s1 * 8]);
  __syncthreads();

  const int NT = K >> 5;
  for (int t = 0; t < NT; ++t) {
    const int cur = t & 1;
    if (t + 1 < NT) {   // issue next-tile loads BEFORE computing this tile
      const int kt = (t + 1) << 5;
      gld16(Ag0 + kt, &As[cur ^ 1][s0 * 8]);
      gld16(Ag1 + kt, &As[cur ^ 1][s1 * 8]);
      gld16(Bg0 + kt, &Bs[cur ^ 1][s0 * 8]);
      gld16(Bg1 + kt, &Bs[cur ^ 1][s1 * 8]);
    }
    const u16* Ar = &As[cur][aoff];
    const u16* Br = &Bs[cur][boff];
    bf16x8 af[4], bv[4];
#pragma unroll
    for (int i = 0; i < 4; ++i) {
      af[i] = *(const bf16x8*)(Ar + i * 16 * 32);
      bv[i] = *(const bf16x8*)(Br + i * 16 * 32);
    }
#pragma unroll
    for (int mi = 0; mi < 4; ++mi)
#pragma unroll
      for (int ni = 0; ni < 4; ++ni)
        acc[mi][ni] = __builtin_amdgcn_mfma_f32_16x16x32_bf16(
            af[mi], bv[ni], acc[mi][ni], 0, 0, 0);
    __syncthreads();  // drains vmcnt(0): prefetched tile t+1 is now in LDS
  }

  const int gr0 = m0 + wy * 64 + quad * 4;
  const int gc0 = n0 + wx * 64 + l16;
#pragma unroll
  for (int ni = 0; ni < 4; ++ni) {
    const int gc = gc0 + ni * 16;
    const float bvs = bias[gc];
#pragma unroll
    for (int mi = 0; mi < 4; ++mi) {
      const int gr = gr0 + mi * 16;
      f32x4 a = acc[mi][ni];
#pragma unroll
      for (int e = 0; e < 4; ++e) {
        float v = a[e] + bvs;
        const size_t idx = (size_t)(gr + e) * N + gc;
        if (EPI == 1) v += res[idx];
        else if (EPI == 2) v = 0.5f * v * (1.f + erff(v * 0.70710678118654752f));
        if (OBF) ((u16*)Cout)[idx] = f2bf(v);
        else     ((float*)Cout)[idx] = v;
      }
    }
  }
}

// ---------- MFMA windowed attention: one WAVE per (window, head) ----------
// 2 waves/block (private LDS P-buffers, no barriers). Q,K,V fragments loaded
// directly from global in MFMA layouts. S = Q@K^T (25 mfma), register softmax
// (shfl_xor over l16 group), P -> LDS (bf16, stride 104: 16B-aligned rows,
// bank period 8 => <=2-way), O = P@V (30 mfma), store window-reversed.
#define PSTR 104
__global__ __launch_bounds__(128)
void attn_mfma(const u16* __restrict__ qkv, u16* __restrict__ onat)
{
  __shared__ __bf16 Pb[2][80 * PSTR];

  const int tid  = threadIdx.x;
  const int wave = tid >> 6, lane = tid & 63;
  const int quad = lane >> 4, l16 = lane & 15;
  const int pair = blockIdx.x * 2 + wave;     // [0, 8192)
  const int nw   = pair >> 3, head = pair & 7;
  const size_t base = (size_t)nw * 77 * 768;
  const int hoff = head * 32;
  __bf16* P = Pb[wave];

  // ---- zero P cols 80..95 (NaN-safety for padded K-steps) ----
  {
    uint4 z = {0, 0, 0, 0};
    for (int r = lane; r < 80; r += 64) {
      *(uint4*)(P + r * PSTR + 80) = z;
      *(uint4*)(P + r * PSTR + 88) = z;
    }
  }

  // ---- Q, K fragments straight from global (lane l16 = token row) ----
  bf16x8 qf[5], kf[5];
  const u16* qp = qkv + base + hoff + quad * 8;
#pragma unroll
  for (int mi = 0; mi < 5; ++mi) {
    const size_t row = (size_t)(l16 + 16 * mi) * 768;
    qf[mi] = *(const bf16x8*)(qp + row);          // q block
    kf[mi] = *(const bf16x8*)(qp + row + 256);    // k block
  }

  // ---- scores S[80][80] in 25 C-tiles ----
  f32x4 s[5][5];
#pragma unroll
  for (int mi = 0; mi < 5; ++mi)
#pragma unroll
    for (int ni = 0; ni < 5; ++ni) {
      f32x4 z = {0.f, 0.f, 0.f, 0.f};
      s[mi][ni] = z;
    }
#pragma unroll
  for (int mi = 0; mi < 5; ++mi)
#pragma unroll
    for (int ni = 0; ni < 5; ++ni)
      s[mi][ni] = __builtin_amdgcn_mfma_f32_16x16x32_bf16(
          qf[mi], kf[ni], s[mi][ni], 0, 0, 0);

  // ---- V fragments (b-layout: lane l16 = d, k = quad*8+jj); k>=77 -> 0 ----
  bf16x8 vf[3][2];
  {
    const __bf16* vbb = (const __bf16*)(qkv + base + 512 + hoff + l16);
#pragma unroll
    for (int ks = 0; ks < 3; ++ks)
#pragma unroll
      for (int ni = 0; ni < 2; ++ni)
#pragma unroll
        for (int jj = 0; jj < 8; ++jj) {
          const int k = ks * 32 + quad * 8 + jj;
          vf[ks][ni][jj] = (k < 77) ? vbb[(size_t)k * 768 + 16 * ni] : (__bf16)0.f;
        }
  }

  // ---- mask cols j >= 77 (j = l16 + 16*ni; only ni==4, l16>=13) ----
  if (l16 >= 13) {
#pragma unroll
    for (int mi = 0; mi < 5; ++mi)
#pragma unroll
      for (int e = 0; e < 4; ++e) s[mi][4][e] = -1e30f;
  }

  // ---- register softmax per row (row = quad*4+e+16*mi) ----
  const float c = 0.17677669529663687f * 1.4426950408889634f;  // scale*log2(e)
  float inv[5][4];
#pragma unroll
  for (int mi = 0; mi < 5; ++mi)
#pragma unroll
    for (int e = 0; e < 4; ++e) {
      float mx = s[mi][0][e];
#pragma unroll
      for (int ni = 1; ni < 5; ++ni) mx = fmaxf(mx, s[mi][ni][e]);
#pragma unroll
      for (int off = 1; off < 16; off <<= 1) mx = fmaxf(mx, __shfl_xor(mx, off));
      float sum = 0.f;
#pragma unroll
      for (int ni = 0; ni < 5; ++ni) {
        const float ev = exp2f((s[mi][ni][e] - mx) * c);
        s[mi][ni][e] = ev;
        sum += ev;
      }
#pragma unroll
      for (int off = 1; off < 16; off <<= 1) sum += __shfl_xor(sum, off);
      inv[mi][e] = 1.f / sum;
    }

  // ---- P -> LDS (bf16), A-operand layout [m][k] ----
#pragma unroll
  for (int mi = 0; mi < 5; ++mi)
#pragma unroll
    for (int e = 0; e < 4; ++e) {
      const int m = quad * 4 + e + 16 * mi;
#pragma unroll
      for (int ni = 0; ni < 5; ++ni)
        P[m * PSTR + l16 + 16 * ni] = (__bf16)(s[mi][ni][e] * inv[mi][e]);
    }

  // ---- O = P @ V ----
  f32x4 o[5][2];
#pragma unroll
  for (int mi = 0; mi < 5; ++mi)
#pragma unroll
    for (int ni = 0; ni < 2; ++ni) {
      f32x4 z = {0.f, 0.f, 0.f, 0.f};
      o[mi][ni] = z;
    }
#pragma unroll
  for (int ks = 0; ks < 3; ++ks)
#pragma unroll
    for (int mi = 0; mi < 5; ++mi) {
      const bf16x8 af = *(const bf16x8*)(P + (l16 + 16 * mi) * PSTR + ks * 32 + quad * 8);
#pragma unroll
      for (int ni = 0; ni < 2; ++ni)
        o[mi][ni] = __builtin_amdgcn_mfma_f32_16x16x32_bf16(
            af, vf[ks][ni], o[mi][ni], 0, 0, 0);
    }

  // ---- store O, window-reversed, bf16 ----
  const int b  = nw >> 7;
  const int ih = (nw >> 4) & 7;
  const int iw = nw & 15;
#pragma unroll
  for (int mi = 0; mi < 5; ++mi)
#pragma unroll
    for (int e = 0; e < 4; ++e) {
      const int t = quad * 4 + e + 16 * mi;
      if (t < 77) {
        const int rr = t / 11, cc = t - rr * 11;
        const int y = ih * 7 + rr, xc = iw * 11 + cc;
        const size_t nat = (size_t)b * 9856 + (size_t)y * 176 + xc;
        u16* dst = onat + nat * DIM + hoff + l16;
        dst[0]  = f2bf(o[mi][0][e]);
        dst[16] = f2bf(o[mi][1][e]);
      }
    }
}

// ---------- launcher ----------
extern "C" void kernel_launch(void* const* d_in, const int* in_sizes, int n_in,
                              void* d_out, int out_size, void* d_ws, size_t ws_size,
                              hipStream_t stream)
{
  (void)in_sizes; (void)n_in; (void)out_size; (void)ws_size;
  const float* x    = (const float*)d_in[0];
  const float* g1   = (const float*)d_in[1];
  const float* b1   = (const float*)d_in[2];
  const float* wqkv = (const float*)d_in[3];
  const float* bqkv = (const float*)d_in[4];
  const float* wout = (const float*)d_in[5];
  const float* bout = (const float*)d_in[6];
  const float* g2   = (const float*)d_in[7];
  const float* b2   = (const float*)d_in[8];
  const float* w1   = (const float*)d_in[9];
  const float* bf1  = (const float*)d_in[10];
  const float* w2   = (const float*)d_in[11];
  const float* bf2  = (const float*)d_in[12];

  char* ws = (char*)d_ws;
  u16*   qkv  = (u16*)(ws);                 // M*768*2 = 121110528  (reused: h = M*512*2)
  u16*   xn   = (u16*)(ws + 121110528);     // M*256*2 =  40370176  (reused: xn2)
  u16*   onat = (u16*)(ws + 161480704);     // M*256*2 =  40370176
  u16*   wb   = (u16*)(ws + 201850880);     // 524288*2 = 1048576
  u16*   wqkv_b = wb;
  u16*   wout_b = wb + 196608;
  u16*   w1_b   = wb + 262144;
  u16*   w2_b   = wb + 393216;
  float* x2   = (float*)d_out;              // x2 lives in d_out

  cvt_w<<<512, 256, 0, stream>>>(wqkv, wout, w1, w2, wb);
  ln_k<true><<<19712, 256, 0, stream>>>(x, g1, b1, xn);
  gemm_mfma<0, 1><<<dim3(6, 616), 256, 0, stream>>>(xn, wqkv_b, bqkv, nullptr, qkv, 768, 256);
  attn_mfma<<<4096, 128, 0, stream>>>(qkv, onat);
  gemm_mfma<1, 0><<<dim3(2, 616), 256, 0, stream>>>(onat, wout_b, bout, x, x2, 256, 256);
  ln_k<false><<<19712, 256, 0, stream>>>(x2, g2, b2, xn);
  gemm_mfma<2, 1><<<dim3(4, 616), 256, 0, stream>>>(xn, w1_b, bf1, nullptr, qkv, 512, 256);
  gemm_mfma<1, 0><<<dim3(2, 616), 256, 0, stream>>>(qkv, w2_b, bf2, x2, x2, 256, 512);
}